// Round 6
// baseline (313.945 us; speedup 1.0000x reference)
//
#include <hip/hip_runtime.h>
#include <hip/hip_bf16.h>

typedef __hip_bfloat16 bf16;
typedef __attribute__((ext_vector_type(8))) short bf16x8;   // MFMA A/B frag (8 bf16)
typedef __attribute__((ext_vector_type(4))) float f32x4;    // MFMA C/D frag

#define LN_EPS 1e-5f
#define ATT_EPS 1e-8f
#define QSCALE 0.08838834764831845f

__device__ __forceinline__ float bflo(unsigned u){ union{unsigned i;float f;}c; c.i=u<<16; return c.f; }
__device__ __forceinline__ float bfhi(unsigned u){ union{unsigned i;float f;}c; c.i=u&0xffff0000u; return c.f; }
__device__ __forceinline__ float bf2f(bf16 h){ return __bfloat162float(h); }
__device__ __forceinline__ unsigned f2bfbits(float f){
    bf16 h = __float2bfloat16(f);
    unsigned short s; __builtin_memcpy(&s, &h, 2);
    return (unsigned)s;
}
__device__ __forceinline__ int detect_isf(const void* niw){
    unsigned u0; __builtin_memcpy(&u0, niw, 4);
    return (u0 == 0x3F800000u) ? 1 : 0;
}

__device__ __forceinline__ float getv(const void* p, long i, int isf){
    if (isf) return ((const float*)p)[i];
    return bf2f(((const bf16*)p)[i]);
}
__device__ __forceinline__ void get8(const void* p, long i, int isf, float* o){
    if (isf){
        __builtin_memcpy(o, (const float*)p + i, 32);
    } else {
        unsigned u[4];
        __builtin_memcpy(u, (const bf16*)p + i, 16);
        o[0]=bflo(u[0]); o[1]=bfhi(u[0]); o[2]=bflo(u[1]); o[3]=bfhi(u[1]);
        o[4]=bflo(u[2]); o[5]=bfhi(u[2]); o[6]=bflo(u[3]); o[7]=bfhi(u[3]);
    }
}
__device__ __forceinline__ void load4f(const float* p, float* o){ __builtin_memcpy(o, p, 16); }
__device__ __forceinline__ void store4f(float* p, const float* v){ __builtin_memcpy(p, v, 16); }

__device__ __forceinline__ void wred2(float& a, float& b){
    #pragma unroll
    for (int m = 32; m > 0; m >>= 1){
        a += __shfl_xor(a, m, 64);
        b += __shfl_xor(b, m, 64);
    }
}

// ======================================================================
// k_prep_d: slot init + LN + direct phaseD. grid 160, 256 thr.
// (R5-verified; P2 zeroing dropped — P2p is write-before-read now)
// ======================================================================
__global__ __launch_bounds__(256) void k_prep_d(
        const void* __restrict__ noise, const void* __restrict__ smu,
        const void* __restrict__ sls, const void* __restrict__ nsw,
        const void* __restrict__ nsb, const void* __restrict__ niw,
        const void* __restrict__ nib, const void* __restrict__ Wq,
        const void* __restrict__ Wk, float* __restrict__ slots,
        bf16* __restrict__ wkqb, float* __restrict__ Ug, float* __restrict__ Vg,
        float* __restrict__ t0g, float* __restrict__ t1g){
    int isf = detect_isf(niw);
    int bs = blockIdx.x, t = threadIdx.x;
    int b = bs/10, s = bs - b*10;
    __shared__ __align__(16) float shlns[128];
    __shared__ __align__(16) float sq2[2][128];
    __shared__ __align__(16) float qv[128];
    __shared__ float red[2][2];
    __shared__ float redUV[8];
    int wid = t >> 6, lane = t & 63;

    if (t < 128){
        float sv = getv(smu,t,isf) + __expf(getv(sls,t,isf)) * getv(noise,(long)bs*128+t,isf);
        slots[bs*128 + t] = sv;
        shlns[t] = sv;
        float su = sv, sqv = sv*sv;
        wred2(su, sqv);
        if (lane == 0){ red[wid][0]=su; red[wid][1]=sqv; }
    }
    __syncthreads();
    if (t < 128){
        float su = red[0][0]+red[1][0], sqv = red[0][1]+red[1][1];
        float m = su*(1.f/128.f), var = sqv*(1.f/128.f) - m*m;
        float ri = rsqrtf(var + LN_EPS);
        shlns[t] = (shlns[t] - m)*ri*getv(nsw,t,isf) + getv(nsb,t,isf);
    }
    __syncthreads();
    {
        int d = t & 127, half = t >> 7;
        float a = 0.f;
        #pragma unroll 8
        for (int dp = half*64; dp < half*64 + 64; dp++)
            a += shlns[dp]*getv(Wq, (long)dp*128 + d, isf);
        sq2[half][d] = a;
    }
    __syncthreads();
    if (t < 128) qv[t] = (sq2[0][t] + sq2[1][t]) * QSCALE;
    __syncthreads();
    {
        float kqc = 0.f;
        #pragma unroll
        for (int ch = 0; ch < 16; ch++){
            float w8[8]; get8(Wk, (long)t*128 + ch*8, isf, w8);
            #pragma unroll
            for (int j=0;j<8;j++) kqc += qv[ch*8+j]*w8[j];
        }
        float wc = getv(niw,t,isf), bc = getv(nib,t,isf);
        float wkq = wc*kqc, vq = bc*kqc;
        float uu = wkq, vv = vq;
        wred2(uu, vv);
        if (lane == 0){ redUV[wid*2] = uu; redUV[wid*2+1] = vv; }
        wkqb[((long)b*16 + s)*256 + t] = __float2bfloat16(wkq);
        __syncthreads();
        if (t == 0){
            Ug[bs] = redUV[0] + redUV[2] + redUV[4] + redUV[6];
            Vg[bs] = redUV[1] + redUV[3] + redUV[5] + redUV[7];
            t0g[bs] = 0.f; t1g[bs] = 0.f;
        }
    }
    if (s == 0){
        #pragma unroll
        for (int r = 10; r < 16; r++)
            wkqb[((long)b*16 + r)*256 + t] = __float2bfloat16(0.f);
    }
}

// ======================================================================
// k_attn9: dual-staged tile (sxn n-major + sxT c-major), MFMA logits,
// hi/lo MFMA phase-2 with per-tile P2p partial stores (no atomics on P2).
// grid (64 tiles, 16 b), 256 thr. LDS ~76 KB -> 2 blocks/CU.
// ======================================================================
__global__ __launch_bounds__(256) void k_attn9(
        const void* __restrict__ obs, const bf16* __restrict__ wkqb,
        const float* __restrict__ Ug, const float* __restrict__ Vg,
        const void* __restrict__ niw, float* __restrict__ P2p,
        float* __restrict__ t0g, float* __restrict__ t1g){
    int isf = detect_isf(niw);
    int tile = blockIdx.x, b = blockIdx.y, t = threadIdx.x;
    int w = t >> 6, l = t & 63;
    __shared__ unsigned sxn[64*132];                 // x tile n-major [px][132 dw]
    __shared__ __align__(16) short sxT[256*72];      // x tile c-major [c][72] (64 used)
    __shared__ __align__(16) short attnTh[16*72];    // attn*ri hi  [s][72]
    __shared__ __align__(16) short attnTl[16*72];    // attn*ri lo  [s][72]
    __shared__ float muri[128];
    __shared__ float denp0[4][16], denp1[4][16];

    // zero attnT rows s=10..15 (shorts [720,1152) == dwords [360,576))
    if (t < 216){
        ((unsigned*)attnTh)[360 + t] = 0u;
        ((unsigned*)attnTl)[360 + t] = 0u;
    }

    // stage obs tile -> sxn (n-major) and sxT (c-major)
    if (isf){
        const float* gx = (const float*)obs + ((long)b*4096 + tile*64)*256;
        #pragma unroll
        for (int i = 0; i < 8; i++){
            int Ld = t*4 + i*1024;
            int px = Ld >> 7, col = Ld & 127;
            float f8[8];
            __builtin_memcpy(f8, gx + (long)px*256 + col*2, 32);
            unsigned pk[4];
            #pragma unroll
            for (int k2=0;k2<4;k2++){
                unsigned b0 = f2bfbits(f8[2*k2]), b1 = f2bfbits(f8[2*k2+1]);
                pk[k2] = (b1 << 16) | b0;
                sxT[(col*2 + 2*k2    )*72 + px] = (short)b0;
                sxT[(col*2 + 2*k2 + 1)*72 + px] = (short)b1;
            }
            __builtin_memcpy(&sxn[px*132 + col], pk, 16);
        }
    } else {
        const unsigned* gx = (const unsigned*)obs + ((long)b*4096 + tile*64)*128;
        #pragma unroll
        for (int i = 0; i < 8; i++){
            int Ld = t*4 + i*1024;
            int px = Ld >> 7, col = Ld & 127;
            unsigned tmp[4];
            __builtin_memcpy(tmp, gx + Ld, 16);
            #pragma unroll
            for (int k2=0;k2<4;k2++){
                sxT[(col*2 + 2*k2    )*72 + px] = (short)(tmp[k2] & 0xffffu);
                sxT[(col*2 + 2*k2 + 1)*72 + px] = (short)(tmp[k2] >> 16);
            }
            __builtin_memcpy(&sxn[px*132 + col], tmp, 16);
        }
    }
    // B-frags (wkq) for logits
    bf16x8 bfr[8];
    {
        int s = l & 15, q = (l >> 4) & 3;
        const bf16* base = wkqb + ((long)b*16 + s)*256 + q*8;
        #pragma unroll
        for (int ks = 0; ks < 8; ks++)
            __builtin_memcpy(&bfr[ks], base + ks*32, 16);
    }
    __syncthreads();

    // inline LN stats per px
    {
        int px = t >> 2, q = t & 3;
        float su = 0.f, sq = 0.f;
        #pragma unroll
        for (int j = 0; j < 8; j++){
            unsigned d4[4];
            __builtin_memcpy(d4, &sxn[px*132 + q*32 + j*4], 16);
            #pragma unroll
            for (int k2=0;k2<4;k2++){
                float a0 = bflo(d4[k2]), a1 = bfhi(d4[k2]);
                su += a0 + a1; sq += a0*a0 + a1*a1;
            }
        }
        su += __shfl_xor(su,1,64); sq += __shfl_xor(sq,1,64);
        su += __shfl_xor(su,2,64); sq += __shfl_xor(sq,2,64);
        if (q == 0){
            float m = su*(1.f/256.f);
            float ri = rsqrtf(sq*(1.f/256.f) - m*m + LN_EPS);
            muri[px*2] = m; muri[px*2+1] = ri;
        }
    }
    __syncthreads();

    // logits MFMA: R[16px][16s]
    f32x4 acc = {0.f,0.f,0.f,0.f};
    {
        int m = l & 15, q = (l >> 4) & 3;
        int rowbase = (w*16 + m)*132;
        #pragma unroll
        for (int ks = 0; ks < 8; ks++){
            bf16x8 af;
            __builtin_memcpy(&af, &sxn[rowbase + ks*16 + q*4], 16);
            acc = __builtin_amdgcn_mfma_f32_16x16x32_bf16(af, bfr[ks], acc, 0, 0, 0);
        }
    }

    // softmax + attnT (hi/lo) + t0/t1 partials
    {
        int col = l & 15, q = (l >> 4) & 3;
        float Uv = 0.f, Vv = 0.f;
        if (col < 10){ Uv = Ug[b*10 + col]; Vv = Vg[b*10 + col]; }
        float pden0 = 0.f, pden1 = 0.f;
        #pragma unroll
        for (int reg = 0; reg < 4; reg++){
            int px = w*16 + q*4 + reg;
            float mr[2]; __builtin_memcpy(mr, &muri[px*2], 8);
            float lg = (col < 10) ? (mr[1]*acc[reg] - mr[1]*mr[0]*Uv + Vv) : -1e30f;
            float mx = lg;
            mx = fmaxf(mx, __shfl_xor(mx,1,64));
            mx = fmaxf(mx, __shfl_xor(mx,2,64));
            mx = fmaxf(mx, __shfl_xor(mx,4,64));
            mx = fmaxf(mx, __shfl_xor(mx,8,64));
            float e = (col < 10) ? __expf(lg - mx) : 0.f;
            float sm = e;
            sm += __shfl_xor(sm,1,64);
            sm += __shfl_xor(sm,2,64);
            sm += __shfl_xor(sm,4,64);
            sm += __shfl_xor(sm,8,64);
            float a = e / sm;
            if (col < 10){
                float ar = a*mr[1];
                unsigned ah = f2bfbits(ar);
                attnTh[col*72 + px] = (short)ah;
                attnTl[col*72 + px] = (short)f2bfbits(ar - bflo(ah));
            }
            pden0 += a;
            pden1 += a*mr[1]*mr[0];
        }
        pden0 += __shfl_xor(pden0,16,64); pden0 += __shfl_xor(pden0,32,64);
        pden1 += __shfl_xor(pden1,16,64); pden1 += __shfl_xor(pden1,32,64);
        if (l < 10){ denp0[w][l] = pden0; denp1[w][l] = pden1; }
    }
    __syncthreads();
    if (t < 10){
        atomicAdd(&t0g[b*10 + t], denp0[0][t]+denp0[1][t]+denp0[2][t]+denp0[3][t]);
        atomicAdd(&t1g[b*10 + t], denp1[0][t]+denp1[1][t]+denp1[2][t]+denp1[3][t]);
    }

    // phase 2 via MFMA: P2[s][c] = sum_n attnT[s][n]*x[n][c], per-tile partials
    {
        int q = l >> 4, j = l & 15;
        bf16x8 ah0, ah1, al0, al1;
        __builtin_memcpy(&ah0, &attnTh[j*72 + q*8], 16);
        __builtin_memcpy(&ah1, &attnTh[j*72 + 32 + q*8], 16);
        __builtin_memcpy(&al0, &attnTl[j*72 + q*8], 16);
        __builtin_memcpy(&al1, &attnTl[j*72 + 32 + q*8], 16);
        #pragma unroll
        for (int i = 0; i < 4; i++){
            int c = w*64 + i*16 + j;
            bf16x8 bx0, bx1;
            __builtin_memcpy(&bx0, &sxT[c*72 + q*8], 16);
            __builtin_memcpy(&bx1, &sxT[c*72 + 32 + q*8], 16);
            f32x4 pa = {0.f,0.f,0.f,0.f};
            pa = __builtin_amdgcn_mfma_f32_16x16x32_bf16(ah0, bx0, pa, 0,0,0);
            pa = __builtin_amdgcn_mfma_f32_16x16x32_bf16(al0, bx0, pa, 0,0,0);
            pa = __builtin_amdgcn_mfma_f32_16x16x32_bf16(ah1, bx1, pa, 0,0,0);
            pa = __builtin_amdgcn_mfma_f32_16x16x32_bf16(al1, bx1, pa, 0,0,0);
            #pragma unroll
            for (int reg = 0; reg < 4; reg++){
                int s = q*4 + reg;
                if (s < 10)
                    P2p[((long)(b*10 + s)*64 + tile)*256 + c] = pa[reg];
            }
        }
    }
}

// ======================================================================
// k_slot3: slot update (P2p tile-reduce) + direct phaseD + fused heads.
// grid 160, 256 thr.
// ======================================================================
__global__ __launch_bounds__(256) void k_slot3(
        float* __restrict__ slots, const float* __restrict__ P2p,
        float* __restrict__ t0g, float* __restrict__ t1g,
        const void* __restrict__ Wv,
        const void* __restrict__ nmw, const void* __restrict__ nmb,
        const void* __restrict__ w1, const void* __restrict__ b1,
        const void* __restrict__ w2, const void* __restrict__ b2,
        const void* __restrict__ nsw, const void* __restrict__ nsb,
        const void* __restrict__ niw, const void* __restrict__ nib,
        const void* __restrict__ pw1, const void* __restrict__ pb1,
        const void* __restrict__ pw2, const void* __restrict__ pb2,
        const void* __restrict__ tw, const void* __restrict__ tb,
        const void* __restrict__ Wq, const void* __restrict__ Wk,
        bf16* __restrict__ wkqb, float* __restrict__ Ug, float* __restrict__ Vg,
        void* __restrict__ out, int last){
    int isf = detect_isf(niw);
    int bs = blockIdx.x, t = threadIdx.x;
    int b = bs/10, s = bs - b*10;
    __shared__ __align__(16) float pr[256];
    __shared__ __align__(16) float redA[16*128];
    __shared__ __align__(16) float redB[8*256];
    __shared__ __align__(16) float redT[8*32];
    __shared__ __align__(16) float hld[128];
    __shared__ __align__(16) float hid[256];
    __shared__ __align__(16) float shlns[128];
    __shared__ float red[4][2];
    __shared__ float redUV[8];

    float t0v = t0g[bs], t1v = t1g[bs];
    float wc = getv(niw,t,isf), bcv = getv(nib,t,isf);
    {
        const float* pp = P2p + ((long)bs*64)*256 + t;
        float u = 0.f;
        #pragma unroll 8
        for (int tl = 0; tl < 64; tl++) u += pp[tl*256];
        pr[t] = (u - t1v)*wc + t0v*bcv;
    }
    __syncthreads();

    {
        int g = t & 15, ks = t >> 4;
        int d0 = g*8;
        float a8[8] = {0,0,0,0,0,0,0,0};
        #pragma unroll
        for (int j=0;j<16;j++){
            int c2 = ks*16 + j;
            float w8[8]; get8(Wv, (long)c2*128 + d0, isf, w8);
            float pv = pr[c2];
            #pragma unroll
            for (int k=0;k<8;k++) a8[k] += pv*w8[k];
        }
        store4f(&redA[ks*128 + d0], a8);
        store4f(&redA[ks*128 + d0 + 4], a8+4);
    }
    __syncthreads();
    float dv = t0v + ATT_EPS;
    float sn = 0.f;
    if (t < 128){
        float u = 0.f;
        #pragma unroll
        for (int ks=0;ks<16;ks++) u += redA[ks*128 + t];
        sn = slots[bs*128 + t] + u/dv;
    }
    float v = (t < 128) ? sn : 0.f;
    float su = v, sq = v*v;
    wred2(su, sq);
    int wid = t >> 6, lane = t & 63;
    if (lane == 0){ red[wid][0]=su; red[wid][1]=sq; }
    __syncthreads();
    su = red[0][0]+red[1][0]+red[2][0]+red[3][0];
    sq = red[0][1]+red[1][1]+red[2][1]+red[3][1];
    float mu = su*(1.f/128.f), var = sq*(1.f/128.f) - mu*mu;
    float rinv = rsqrtf(var + LN_EPS);
    if (t < 128) hld[t] = (v-mu)*rinv*getv(nmw,t,isf) + getv(nmb,t,isf);
    __syncthreads();

    {
        int g = t & 31, ks = t >> 5;
        int h0 = g*8;
        float a8[8] = {0,0,0,0,0,0,0,0};
        #pragma unroll
        for (int j=0;j<16;j++){
            int d = ks*16 + j;
            float w8[8]; get8(w1, (long)d*256 + h0, isf, w8);
            float hv = hld[d];
            #pragma unroll
            for (int k=0;k<8;k++) a8[k] += hv*w8[k];
        }
        store4f(&redB[ks*256 + h0], a8);
        store4f(&redB[ks*256 + h0 + 4], a8+4);
    }
    __syncthreads();
    {
        float hb = getv(b1,t,isf);
        #pragma unroll
        for (int ks=0;ks<8;ks++) hb += redB[ks*256 + t];
        hid[t] = fmaxf(hb, 0.f);
    }
    __syncthreads();
    {
        int g = t & 15, ks = t >> 4;
        int d0 = g*8;
        float a8[8] = {0,0,0,0,0,0,0,0};
        #pragma unroll
        for (int j=0;j<16;j++){
            int h = ks*16 + j;
            float w8[8]; get8(w2, (long)h*128 + d0, isf, w8);
            float hv = hid[h];
            #pragma unroll
            for (int k=0;k<8;k++) a8[k] += hv*w8[k];
        }
        store4f(&redA[ks*128 + d0], a8);
        store4f(&redA[ks*128 + d0 + 4], a8+4);
    }
    __syncthreads();
    float v2 = 0.f;
    if (t < 128){
        float o = getv(b2,t,isf);
        #pragma unroll
        for (int ks=0;ks<16;ks++) o += redA[ks*128 + t];
        v2 = sn + o;
    }

    if (!last){
        if (t < 128) slots[bs*128 + t] = v2;
        float s2 = v2, ss2 = v2*v2;
        wred2(s2, ss2);
        if (lane == 0){ red[wid][0]=s2; red[wid][1]=ss2; }
        __syncthreads();
        s2 = red[0][0]+red[1][0]+red[2][0]+red[3][0];
        ss2 = red[0][1]+red[1][1]+red[2][1]+red[3][1];
        float mu2 = s2*(1.f/128.f), var2 = ss2*(1.f/128.f) - mu2*mu2;
        float ri2 = rsqrtf(var2 + LN_EPS);
        if (t < 128)
            shlns[t] = (v2 - mu2)*ri2*getv(nsw,t,isf) + getv(nsb,t,isf);
        __syncthreads();
        // ---- direct phaseD ----
        {
            int d = t & 127, half = t >> 7;
            float a = 0.f;
            #pragma unroll 8
            for (int dp = half*64; dp < half*64 + 64; dp++)
                a += shlns[dp]*getv(Wq, (long)dp*128 + d, isf);
            redA[half*128 + d] = a;
        }
        __syncthreads();
        if (t < 128) hld[t] = (redA[t] + redA[128 + t]) * QSCALE;
        __syncthreads();
        {
            float kqc = 0.f;
            #pragma unroll
            for (int ch = 0; ch < 16; ch++){
                float w8[8]; get8(Wk, (long)t*128 + ch*8, isf, w8);
                #pragma unroll
                for (int j=0;j<8;j++) kqc += hld[ch*8+j]*w8[j];
            }
            float wcc = getv(niw,t,isf), bcc = getv(nib,t,isf);
            float wkq = wcc*kqc, vq = bcc*kqc;
            float uu = wkq, vv = vq;
            wred2(uu, vv);
            if (lane == 0){ redUV[wid*2] = uu; redUV[wid*2+1] = vv; }
            wkqb[((long)b*16 + s)*256 + t] = __float2bfloat16(wkq);
            __syncthreads();
            if (t == 0){
                Ug[bs] = redUV[0] + redUV[2] + redUV[4] + redUV[6];
                Vg[bs] = redUV[1] + redUV[3] + redUV[5] + redUV[7];
                t0g[bs] = 0.f; t1g[bs] = 0.f;
            }
        }
    } else {
        if (t < 128) shlns[t] = v2;
        __syncthreads();
        {
            int g = t & 31, ks = t >> 5;
            int h0 = g*8;
            float a8[8] = {0,0,0,0,0,0,0,0};
            #pragma unroll
            for (int j=0;j<16;j++){
                int d = ks*16 + j;
                float w8[8]; get8(pw1, (long)d*256 + h0, isf, w8);
                float hv = shlns[d];
                #pragma unroll
                for (int k=0;k<8;k++) a8[k] += hv*w8[k];
            }
            store4f(&redB[ks*256 + h0], a8);
            store4f(&redB[ks*256 + h0 + 4], a8+4);
        }
        __syncthreads();
        {
            float hb = getv(pb1,t,isf);
            #pragma unroll
            for (int ks=0;ks<8;ks++) hb += redB[ks*256 + t];
            hid[t] = fmaxf(hb, 0.f);
        }
        __syncthreads();
        {
            int g = t & 15, ks = t >> 4;
            int d0 = g*8;
            float a8[8] = {0,0,0,0,0,0,0,0};
            #pragma unroll
            for (int j=0;j<16;j++){
                int h = ks*16 + j;
                float w8[8]; get8(pw2, (long)h*128 + d0, isf, w8);
                float hv = hid[h];
                #pragma unroll
                for (int k=0;k<8;k++) a8[k] += hv*w8[k];
            }
            store4f(&redA[ks*128 + d0], a8);
            store4f(&redA[ks*128 + d0 + 4], a8+4);
        }
        {
            int ot = t & 31, ks = t >> 5;
            float a = 0.f;
            if (ot < 20){
                #pragma unroll
                for (int j=0;j<16;j++){
                    int d = ks*16 + j;
                    a += shlns[d]*getv(tw, (long)d*20 + ot, isf);
                }
            }
            redT[ks*32 + ot] = a;
        }
        __syncthreads();
        if (t < 128){
            float o = getv(pb2,t,isf);
            #pragma unroll
            for (int ks=0;ks<16;ks++) o += redA[ks*128 + t];
            int idx = bs*128 + t;
            if (isf) ((float*)out)[idx] = o; else ((bf16*)out)[idx] = __float2bfloat16(o);
        }
        if (t < 20){
            float o = getv(tb,t,isf);
            #pragma unroll
            for (int ks=0;ks<8;ks++) o += redT[ks*32 + t];
            int idx = 16*10*128 + bs*20 + t;
            if (isf) ((float*)out)[idx] = o; else ((bf16*)out)[idx] = __float2bfloat16(o);
        }
    }
}

extern "C" void kernel_launch(void* const* d_in, const int* in_sizes, int n_in,
                              void* d_out, int out_size, void* d_ws, size_t ws_size,
                              hipStream_t stream) {
    const void* obs   = d_in[0];
    const void* noise = d_in[1];
    const void* smu   = d_in[2];
    const void* sls   = d_in[3];
    const void* niw   = d_in[4];
    const void* nib   = d_in[5];
    const void* nsw   = d_in[6];
    const void* nsb   = d_in[7];
    const void* nmw   = d_in[8];
    const void* nmb   = d_in[9];
    const void* Wq    = d_in[10];
    const void* Wk    = d_in[11];
    const void* Wv    = d_in[12];
    const void* w1    = d_in[13];
    const void* b1    = d_in[14];
    const void* w2    = d_in[15];
    const void* b2    = d_in[16];
    const void* pw1   = d_in[17];
    const void* pb1   = d_in[18];
    const void* pw2   = d_in[19];
    const void* pb2   = d_in[20];
    const void* tw    = d_in[21];
    const void* tb    = d_in[22];

    char* ws = (char*)d_ws;
    float* t0g   = (float*)(ws + 1024);         // 1 KB (160 used)
    float* t1g   = (float*)(ws + 2048);         // 1 KB
    float* Ug    = (float*)(ws + 3072);         // 1 KB
    float* Vg    = (float*)(ws + 4096);         // 1 KB
    float* slots = (float*)(ws + 5120);         // 81920 B
    bf16*  wkqb  = (bf16*) (ws + 87040);        // 131072 B
    float* P2p   = (float*)(ws + 218112);       // 10485760 B  [bs][tile][256]  (~10.7 MB total)

    k_prep_d<<<160, 256, 0, stream>>>(noise, smu, sls, nsw, nsb, niw, nib,
                                      Wq, Wk, slots, wkqb, Ug, Vg, t0g, t1g);
    for (int it = 0; it < 3; it++){
        k_attn9<<<dim3(64, 16), 256, 0, stream>>>(obs, wkqb, Ug, Vg, niw, P2p, t0g, t1g);
        k_slot3<<<160, 256, 0, stream>>>(slots, P2p, t0g, t1g, Wv, nmw, nmb,
                                         w1, b1, w2, b2, nsw, nsb, niw, nib,
                                         pw1, pb1, pw2, pb2, tw, tb, Wq, Wk,
                                         wkqb, Ug, Vg, d_out, (it == 2) ? 1 : 0);
    }
}

// Round 7
// 242.935 us; speedup vs baseline: 1.2923x; 1.2923x over previous
//
#include <hip/hip_runtime.h>
#include <hip/hip_bf16.h>

typedef __hip_bfloat16 bf16;
typedef __attribute__((ext_vector_type(8))) short bf16x8;   // MFMA A/B frag (8 bf16)
typedef __attribute__((ext_vector_type(4))) float f32x4;    // MFMA C/D frag

#define LN_EPS 1e-5f
#define ATT_EPS 1e-8f
#define QSCALE 0.08838834764831845f

__device__ __forceinline__ float bflo(unsigned u){ union{unsigned i;float f;}c; c.i=u<<16; return c.f; }
__device__ __forceinline__ float bfhi(unsigned u){ union{unsigned i;float f;}c; c.i=u&0xffff0000u; return c.f; }
__device__ __forceinline__ float bf2f(bf16 h){ return __bfloat162float(h); }
__device__ __forceinline__ unsigned f2bfbits(float f){
    bf16 h = __float2bfloat16(f);
    unsigned short s; __builtin_memcpy(&s, &h, 2);
    return (unsigned)s;
}
__device__ __forceinline__ int detect_isf(const void* niw){
    unsigned u0; __builtin_memcpy(&u0, niw, 4);
    return (u0 == 0x3F800000u) ? 1 : 0;
}

__device__ __forceinline__ float getv(const void* p, long i, int isf){
    if (isf) return ((const float*)p)[i];
    return bf2f(((const bf16*)p)[i]);
}
__device__ __forceinline__ void get8(const void* p, long i, int isf, float* o){
    if (isf){
        __builtin_memcpy(o, (const float*)p + i, 32);
    } else {
        unsigned u[4];
        __builtin_memcpy(u, (const bf16*)p + i, 16);
        o[0]=bflo(u[0]); o[1]=bfhi(u[0]); o[2]=bflo(u[1]); o[3]=bfhi(u[1]);
        o[4]=bflo(u[2]); o[5]=bfhi(u[2]); o[6]=bflo(u[3]); o[7]=bfhi(u[3]);
    }
}
__device__ __forceinline__ void load4f(const float* p, float* o){ __builtin_memcpy(o, p, 16); }
__device__ __forceinline__ void store4f(float* p, const float* v){ __builtin_memcpy(p, v, 16); }

__device__ __forceinline__ void wred2(float& a, float& b){
    #pragma unroll
    for (int m = 32; m > 0; m >>= 1){
        a += __shfl_xor(a, m, 64);
        b += __shfl_xor(b, m, 64);
    }
}

// ======================================================================
// k_init0: merged gmat + prep (independent workloads, one launch).
//   blocks [0,256):   G[d][c] = scale * sum_d' Wq[d][d']*Wk[c][d']  (c = bid)
//   blocks [256,416): slot init + LN + direct phaseD (q=lns@Wq, kq=q.Wk rows)
//                     + zero P2/t0g/t1g.
// ======================================================================
__global__ __launch_bounds__(256) void k_init0(
        const void* __restrict__ noise, const void* __restrict__ smu,
        const void* __restrict__ sls, const void* __restrict__ nsw,
        const void* __restrict__ nsb, const void* __restrict__ niw,
        const void* __restrict__ nib, const void* __restrict__ Wq,
        const void* __restrict__ Wk, float* __restrict__ G,
        float* __restrict__ slots, bf16* __restrict__ wkqb,
        float* __restrict__ Ug, float* __restrict__ Vg,
        float* __restrict__ P2, float* __restrict__ t0g, float* __restrict__ t1g){
    int isf = detect_isf(niw);
    int bid = blockIdx.x, t = threadIdx.x;
    __shared__ __align__(16) float shlns[128];
    __shared__ __align__(16) float sq2[2][128];
    __shared__ __align__(16) float qv[128];
    __shared__ float red2[2][128];
    __shared__ float red[2][2];
    __shared__ float redUV[8];
    int wid = t >> 6, lane = t & 63;

    if (bid < 256){
        // ---- gmat body (R0-verified) ----
        int c = bid;
        int d = t & 127, half = t >> 7;
        float acc = 0.f;
        #pragma unroll
        for (int ch = 0; ch < 8; ch++){
            int dp = half*64 + ch*8;
            float wq8[8], wk8[8];
            get8(Wq, (long)d*128 + dp, isf, wq8);
            get8(Wk, (long)c*128 + dp, isf, wk8);
            #pragma unroll
            for (int j=0;j<8;j++) acc += wq8[j]*wk8[j];
        }
        red2[half][d] = acc;
        __syncthreads();
        if (t < 128)
            G[(long)t*256 + c] = (red2[0][t] + red2[1][t]) * QSCALE;
        return;
    }

    // ---- prep body (R5-verified direct phaseD; no G dependency) ----
    int bs = bid - 256;
    int b = bs/10, s = bs - b*10;
    if (t < 128){
        float sv = getv(smu,t,isf) + __expf(getv(sls,t,isf)) * getv(noise,(long)bs*128+t,isf);
        slots[bs*128 + t] = sv;
        shlns[t] = sv;
        float su = sv, sqv = sv*sv;
        wred2(su, sqv);
        if (lane == 0){ red[wid][0]=su; red[wid][1]=sqv; }
    }
    __syncthreads();
    if (t < 128){
        float su = red[0][0]+red[1][0], sqv = red[0][1]+red[1][1];
        float m = su*(1.f/128.f), var = sqv*(1.f/128.f) - m*m;
        float ri = rsqrtf(var + LN_EPS);
        shlns[t] = (shlns[t] - m)*ri*getv(nsw,t,isf) + getv(nsb,t,isf);
    }
    __syncthreads();
    {
        int d = t & 127, half = t >> 7;
        float a = 0.f;
        #pragma unroll 8
        for (int dp = half*64; dp < half*64 + 64; dp++)
            a += shlns[dp]*getv(Wq, (long)dp*128 + d, isf);
        sq2[half][d] = a;
    }
    __syncthreads();
    if (t < 128) qv[t] = (sq2[0][t] + sq2[1][t]) * QSCALE;
    __syncthreads();
    {
        float kqc = 0.f;
        #pragma unroll
        for (int ch = 0; ch < 16; ch++){
            float w8[8]; get8(Wk, (long)t*128 + ch*8, isf, w8);
            #pragma unroll
            for (int j=0;j<8;j++) kqc += qv[ch*8+j]*w8[j];
        }
        float wc = getv(niw,t,isf), bc = getv(nib,t,isf);
        float wkq = wc*kqc, vq = bc*kqc;
        float uu = wkq, vv = vq;
        wred2(uu, vv);
        if (lane == 0){ redUV[wid*2] = uu; redUV[wid*2+1] = vv; }
        wkqb[((long)b*16 + s)*256 + t] = __float2bfloat16(wkq);
        P2[bs*256 + t] = 0.f;
        __syncthreads();
        if (t == 0){
            Ug[bs] = redUV[0] + redUV[2] + redUV[4] + redUV[6];
            Vg[bs] = redUV[1] + redUV[3] + redUV[5] + redUV[7];
            t0g[bs] = 0.f; t1g[bs] = 0.f;
        }
    }
    if (s == 0){
        #pragma unroll
        for (int r = 10; r < 16; r++)
            wkqb[((long)b*16 + r)*256 + t] = __float2bfloat16(0.f);
    }
}

// -------- phase D (G-based, R0-verified): from lns (LDS) compute
// kq[c] = sum_d lns[d]*G[d][c]; wkq -> wkqb bf16 row; U,V sums; zero P2/t0/t1.
__device__ __forceinline__ void phaseD(
        int b, int s, int t, const float* shlns, const float* __restrict__ G,
        const void* __restrict__ niw, const void* __restrict__ nib, int isf,
        bf16* __restrict__ wkqb, float* __restrict__ Ug, float* __restrict__ Vg,
        float* __restrict__ P2, float* __restrict__ t0g, float* __restrict__ t1g,
        float* redUV){
    int c = t;
    float kqc = 0.f;
    for (int d0 = 0; d0 < 128; d0 += 8){
        float l8[8];
        load4f(shlns + d0, l8); load4f(shlns + d0 + 4, l8 + 4);
        kqc += l8[0]*G[(long)(d0+0)*256+c] + l8[1]*G[(long)(d0+1)*256+c]
             + l8[2]*G[(long)(d0+2)*256+c] + l8[3]*G[(long)(d0+3)*256+c]
             + l8[4]*G[(long)(d0+4)*256+c] + l8[5]*G[(long)(d0+5)*256+c]
             + l8[6]*G[(long)(d0+6)*256+c] + l8[7]*G[(long)(d0+7)*256+c];
    }
    float wc = getv(niw, c, isf), bc = getv(nib, c, isf);
    float wkq = wc*kqc, vq = bc*kqc;
    float uu = wkq, vv = vq;
    wred2(uu, vv);
    int wid = t >> 6, lane = t & 63;
    if (lane == 0){ redUV[wid*2] = uu; redUV[wid*2+1] = vv; }
    wkqb[((long)b*16 + s)*256 + c] = __float2bfloat16(wkq);
    int bs = b*10 + s;
    P2[bs*256 + c] = 0.f;
    __syncthreads();
    if (t == 0){
        Ug[bs] = redUV[0] + redUV[2] + redUV[4] + redUV[6];
        Vg[bs] = redUV[1] + redUV[3] + redUV[5] + redUV[7];
        t0g[bs] = 0.f; t1g[bs] = 0.f;
    }
}

// ======================================================================
// k_attn5: 64-px tile/block (R0-verified body; local dtype detect).
// grid (64 tiles, 16 b), 256 thr. LDS ~37.9 KB -> 4 blocks/CU
// ======================================================================
__global__ __launch_bounds__(256) void k_attn5(
        const void* __restrict__ obs, const bf16* __restrict__ wkqb,
        const float* __restrict__ Ug, const float* __restrict__ Vg,
        const void* __restrict__ niw, float* __restrict__ P2,
        float* __restrict__ t0g, float* __restrict__ t1g){
    int isf = detect_isf(niw);
    int tile = blockIdx.x, b = blockIdx.y, t = threadIdx.x;
    int w = t >> 6, l = t & 63;
    __shared__ unsigned sxn[64*132];
    __shared__ __align__(16) float attnP[64*12];
    __shared__ float muri[128];
    __shared__ float denp0[4][16], denp1[4][16];

    if (isf){
        const float* gx = (const float*)obs + ((long)b*4096 + tile*64)*256;
        #pragma unroll
        for (int i = 0; i < 8; i++){
            int Ld = t*4 + i*1024;
            int px = Ld >> 7, col = Ld & 127;
            float f8[8];
            __builtin_memcpy(f8, gx + (long)px*256 + col*2, 32);
            unsigned pk[4];
            #pragma unroll
            for (int k2=0;k2<4;k2++)
                pk[k2] = (f2bfbits(f8[2*k2+1])<<16) | f2bfbits(f8[2*k2]);
            __builtin_memcpy(&sxn[px*132 + col], pk, 16);
        }
    } else {
        const unsigned* gx = (const unsigned*)obs + ((long)b*4096 + tile*64)*128;
        #pragma unroll
        for (int i = 0; i < 8; i++){
            int Ld = t*4 + i*1024;
            int px = Ld >> 7, col = Ld & 127;
            unsigned tmp[4];
            __builtin_memcpy(tmp, gx + Ld, 16);
            __builtin_memcpy(&sxn[px*132 + col], tmp, 16);
        }
    }
    bf16x8 bfr[8];
    {
        int s = l & 15, q = (l >> 4) & 3;
        const bf16* base = wkqb + ((long)b*16 + s)*256 + q*8;
        #pragma unroll
        for (int ks = 0; ks < 8; ks++)
            __builtin_memcpy(&bfr[ks], base + ks*32, 16);
    }
    __syncthreads();

    {
        int px = t >> 2, q = t & 3;
        float su = 0.f, sq = 0.f;
        #pragma unroll
        for (int j = 0; j < 8; j++){
            unsigned d4[4];
            __builtin_memcpy(d4, &sxn[px*132 + q*32 + j*4], 16);
            #pragma unroll
            for (int k2=0;k2<4;k2++){
                float a0 = bflo(d4[k2]), a1 = bfhi(d4[k2]);
                su += a0 + a1; sq += a0*a0 + a1*a1;
            }
        }
        su += __shfl_xor(su,1,64); sq += __shfl_xor(sq,1,64);
        su += __shfl_xor(su,2,64); sq += __shfl_xor(sq,2,64);
        if (q == 0){
            float m = su*(1.f/256.f);
            float ri = rsqrtf(sq*(1.f/256.f) - m*m + LN_EPS);
            muri[px*2] = m; muri[px*2+1] = ri;
        }
    }
    __syncthreads();

    f32x4 acc = {0.f,0.f,0.f,0.f};
    {
        int m = l & 15, q = (l >> 4) & 3;
        int rowbase = (w*16 + m)*132;
        #pragma unroll
        for (int ks = 0; ks < 8; ks++){
            bf16x8 af;
            __builtin_memcpy(&af, &sxn[rowbase + ks*16 + q*4], 16);
            acc = __builtin_amdgcn_mfma_f32_16x16x32_bf16(af, bfr[ks], acc, 0, 0, 0);
        }
    }

    {
        int col = l & 15, q = (l >> 4) & 3;
        float Uv = 0.f, Vv = 0.f;
        if (col < 10){ Uv = Ug[b*10 + col]; Vv = Vg[b*10 + col]; }
        float pden0 = 0.f, pden1 = 0.f;
        #pragma unroll
        for (int reg = 0; reg < 4; reg++){
            int px = w*16 + q*4 + reg;
            float mr[2]; __builtin_memcpy(mr, &muri[px*2], 8);
            float lg = (col < 10) ? (mr[1]*acc[reg] - mr[1]*mr[0]*Uv + Vv) : -1e30f;
            float mx = lg;
            mx = fmaxf(mx, __shfl_xor(mx,1,64));
            mx = fmaxf(mx, __shfl_xor(mx,2,64));
            mx = fmaxf(mx, __shfl_xor(mx,4,64));
            mx = fmaxf(mx, __shfl_xor(mx,8,64));
            float e = (col < 10) ? __expf(lg - mx) : 0.f;
            float sm = e;
            sm += __shfl_xor(sm,1,64);
            sm += __shfl_xor(sm,2,64);
            sm += __shfl_xor(sm,4,64);
            sm += __shfl_xor(sm,8,64);
            float a = e / sm;
            if (col < 10) attnP[px*12 + col] = a*mr[1];
            pden0 += a;
            pden1 += a*mr[1]*mr[0];
        }
        pden0 += __shfl_xor(pden0,16,64); pden0 += __shfl_xor(pden0,32,64);
        pden1 += __shfl_xor(pden1,16,64); pden1 += __shfl_xor(pden1,32,64);
        if (l < 10){ denp0[w][l] = pden0; denp1[w][l] = pden1; }
    }
    __syncthreads();
    if (t < 10){
        atomicAdd(&t0g[b*10 + t], denp0[0][t]+denp0[1][t]+denp0[2][t]+denp0[3][t]);
        atomicAdd(&t1g[b*10 + t], denp1[0][t]+denp1[1][t]+denp1[2][t]+denp1[3][t]);
    }

    {
        int c = t, ch = c >> 1, hh = c & 1;
        float pacc[10];
        #pragma unroll
        for (int s=0;s<10;s++) pacc[s]=0.f;
        for (int n = 0; n < 64; n++){
            unsigned d = sxn[n*132 + ch];
            float xv = hh ? bfhi(d) : bflo(d);
            float a[10];
            load4f(&attnP[n*12], a);
            load4f(&attnP[n*12 + 4], a + 4);
            __builtin_memcpy(a + 8, &attnP[n*12 + 8], 8);
            #pragma unroll
            for (int s=0;s<10;s++) pacc[s] += a[s]*xv;
        }
        #pragma unroll
        for (int s=0;s<10;s++) atomicAdd(&P2[b*2560 + s*256 + c], pacc[s]);
    }
}

// ======================================================================
// k_slot: slot update + G-based phaseD + fused heads (R0-verified body,
// flag replaced by local dtype detect). grid 160, 256 thr.
// ======================================================================
__global__ __launch_bounds__(256) void k_slot(
        float* __restrict__ slots, float* __restrict__ P2,
        float* __restrict__ t0g, float* __restrict__ t1g,
        const void* __restrict__ Wv,
        const void* __restrict__ nmw, const void* __restrict__ nmb,
        const void* __restrict__ w1, const void* __restrict__ b1,
        const void* __restrict__ w2, const void* __restrict__ b2,
        const void* __restrict__ nsw, const void* __restrict__ nsb,
        const void* __restrict__ niw, const void* __restrict__ nib,
        const void* __restrict__ pw1, const void* __restrict__ pb1,
        const void* __restrict__ pw2, const void* __restrict__ pb2,
        const void* __restrict__ tw, const void* __restrict__ tb,
        const float* __restrict__ G,
        bf16* __restrict__ wkqb, float* __restrict__ Ug, float* __restrict__ Vg,
        void* __restrict__ out, int last){
    int isf = detect_isf(niw);
    int bs = blockIdx.x, t = threadIdx.x;
    int b = bs/10, s = bs - b*10;
    __shared__ __align__(16) float pr[256];
    __shared__ __align__(16) float redA[16*128];
    __shared__ __align__(16) float redB[8*256];
    __shared__ __align__(16) float redT[8*32];
    __shared__ __align__(16) float hld[128];
    __shared__ __align__(16) float hid[256];
    __shared__ __align__(16) float shlns[128];
    __shared__ float red[4][2];
    __shared__ float redUV[8];

    float t0v = t0g[bs], t1v = t1g[bs];
    float wc = getv(niw,t,isf), bcv = getv(nib,t,isf);
    pr[t] = (P2[bs*256 + t] - t1v)*wc + t0v*bcv;
    __syncthreads();

    {
        int g = t & 15, ks = t >> 4;
        int d0 = g*8;
        float a8[8] = {0,0,0,0,0,0,0,0};
        #pragma unroll
        for (int j=0;j<16;j++){
            int c2 = ks*16 + j;
            float w8[8]; get8(Wv, (long)c2*128 + d0, isf, w8);
            float pv = pr[c2];
            #pragma unroll
            for (int k=0;k<8;k++) a8[k] += pv*w8[k];
        }
        store4f(&redA[ks*128 + d0], a8);
        store4f(&redA[ks*128 + d0 + 4], a8+4);
    }
    __syncthreads();
    float dv = t0v + ATT_EPS;
    float sn = 0.f;
    if (t < 128){
        float u = 0.f;
        #pragma unroll
        for (int ks=0;ks<16;ks++) u += redA[ks*128 + t];
        sn = slots[bs*128 + t] + u/dv;
    }
    float v = (t < 128) ? sn : 0.f;
    float su = v, sq = v*v;
    wred2(su, sq);
    int wid = t >> 6, lane = t & 63;
    if (lane == 0){ red[wid][0]=su; red[wid][1]=sq; }
    __syncthreads();
    su = red[0][0]+red[1][0]+red[2][0]+red[3][0];
    sq = red[0][1]+red[1][1]+red[2][1]+red[3][1];
    float mu = su*(1.f/128.f), var = sq*(1.f/128.f) - mu*mu;
    float rinv = rsqrtf(var + LN_EPS);
    if (t < 128) hld[t] = (v-mu)*rinv*getv(nmw,t,isf) + getv(nmb,t,isf);
    __syncthreads();

    {
        int g = t & 31, ks = t >> 5;
        int h0 = g*8;
        float a8[8] = {0,0,0,0,0,0,0,0};
        #pragma unroll
        for (int j=0;j<16;j++){
            int d = ks*16 + j;
            float w8[8]; get8(w1, (long)d*256 + h0, isf, w8);
            float hv = hld[d];
            #pragma unroll
            for (int k=0;k<8;k++) a8[k] += hv*w8[k];
        }
        store4f(&redB[ks*256 + h0], a8);
        store4f(&redB[ks*256 + h0 + 4], a8+4);
    }
    __syncthreads();
    {
        float hb = getv(b1,t,isf);
        #pragma unroll
        for (int ks=0;ks<8;ks++) hb += redB[ks*256 + t];
        hid[t] = fmaxf(hb, 0.f);
    }
    __syncthreads();

    {
        int g = t & 15, ks = t >> 4;
        int d0 = g*8;
        float a8[8] = {0,0,0,0,0,0,0,0};
        #pragma unroll
        for (int j=0;j<16;j++){
            int h = ks*16 + j;
            float w8[8]; get8(w2, (long)h*128 + d0, isf, w8);
            float hv = hid[h];
            #pragma unroll
            for (int k=0;k<8;k++) a8[k] += hv*w8[k];
        }
        store4f(&redA[ks*128 + d0], a8);
        store4f(&redA[ks*128 + d0 + 4], a8+4);
    }
    __syncthreads();
    float v2 = 0.f;
    if (t < 128){
        float o = getv(b2,t,isf);
        #pragma unroll
        for (int ks=0;ks<16;ks++) o += redA[ks*128 + t];
        v2 = sn + o;
    }

    if (!last){
        if (t < 128) slots[bs*128 + t] = v2;
        float s2 = v2, ss2 = v2*v2;
        wred2(s2, ss2);
        if (lane == 0){ red[wid][0]=s2; red[wid][1]=ss2; }
        __syncthreads();
        s2 = red[0][0]+red[1][0]+red[2][0]+red[3][0];
        ss2 = red[0][1]+red[1][1]+red[2][1]+red[3][1];
        float mu2 = s2*(1.f/128.f), var2 = ss2*(1.f/128.f) - mu2*mu2;
        float ri2 = rsqrtf(var2 + LN_EPS);
        if (t < 128)
            shlns[t] = (v2 - mu2)*ri2*getv(nsw,t,isf) + getv(nsb,t,isf);
        __syncthreads();
        phaseD(b, s, t, shlns, G, niw, nib, isf, wkqb, Ug, Vg, P2, t0g, t1g, redUV);
    } else {
        if (t < 128) shlns[t] = v2;
        __syncthreads();
        {
            int g = t & 31, ks = t >> 5;
            int h0 = g*8;
            float a8[8] = {0,0,0,0,0,0,0,0};
            #pragma unroll
            for (int j=0;j<16;j++){
                int d = ks*16 + j;
                float w8[8]; get8(pw1, (long)d*256 + h0, isf, w8);
                float hv = shlns[d];
                #pragma unroll
                for (int k=0;k<8;k++) a8[k] += hv*w8[k];
            }
            store4f(&redB[ks*256 + h0], a8);
            store4f(&redB[ks*256 + h0 + 4], a8+4);
        }
        __syncthreads();
        {
            float hb = getv(pb1,t,isf);
            #pragma unroll
            for (int ks=0;ks<8;ks++) hb += redB[ks*256 + t];
            hid[t] = fmaxf(hb, 0.f);
        }
        __syncthreads();
        {
            int g = t & 15, ks = t >> 4;
            int d0 = g*8;
            float a8[8] = {0,0,0,0,0,0,0,0};
            #pragma unroll
            for (int j=0;j<16;j++){
                int h = ks*16 + j;
                float w8[8]; get8(pw2, (long)h*128 + d0, isf, w8);
                float hv = hid[h];
                #pragma unroll
                for (int k=0;k<8;k++) a8[k] += hv*w8[k];
            }
            store4f(&redA[ks*128 + d0], a8);
            store4f(&redA[ks*128 + d0 + 4], a8+4);
        }
        {
            int ot = t & 31, ks = t >> 5;
            float a = 0.f;
            if (ot < 20){
                #pragma unroll
                for (int j=0;j<16;j++){
                    int d = ks*16 + j;
                    a += shlns[d]*getv(tw, (long)d*20 + ot, isf);
                }
            }
            redT[ks*32 + ot] = a;
        }
        __syncthreads();
        if (t < 128){
            float o = getv(pb2,t,isf);
            #pragma unroll
            for (int ks=0;ks<16;ks++) o += redA[ks*128 + t];
            int idx = bs*128 + t;
            if (isf) ((float*)out)[idx] = o; else ((bf16*)out)[idx] = __float2bfloat16(o);
        }
        if (t < 20){
            float o = getv(tb,t,isf);
            #pragma unroll
            for (int ks=0;ks<8;ks++) o += redT[ks*32 + t];
            int idx = 16*10*128 + bs*20 + t;
            if (isf) ((float*)out)[idx] = o; else ((bf16*)out)[idx] = __float2bfloat16(o);
        }
    }
}

extern "C" void kernel_launch(void* const* d_in, const int* in_sizes, int n_in,
                              void* d_out, int out_size, void* d_ws, size_t ws_size,
                              hipStream_t stream) {
    const void* obs   = d_in[0];
    const void* noise = d_in[1];
    const void* smu   = d_in[2];
    const void* sls   = d_in[3];
    const void* niw   = d_in[4];
    const void* nib   = d_in[5];
    const void* nsw   = d_in[6];
    const void* nsb   = d_in[7];
    const void* nmw   = d_in[8];
    const void* nmb   = d_in[9];
    const void* Wq    = d_in[10];
    const void* Wk    = d_in[11];
    const void* Wv    = d_in[12];
    const void* w1    = d_in[13];
    const void* b1    = d_in[14];
    const void* w2    = d_in[15];
    const void* b2    = d_in[16];
    const void* pw1   = d_in[17];
    const void* pb1   = d_in[18];
    const void* pw2   = d_in[19];
    const void* pb2   = d_in[20];
    const void* tw    = d_in[21];
    const void* tb    = d_in[22];

    char* ws = (char*)d_ws;
    float* t0g   = (float*)(ws + 1024);         // 1 KB (160 used)
    float* t1g   = (float*)(ws + 2048);         // 1 KB
    float* Ug    = (float*)(ws + 3072);         // 1 KB
    float* Vg    = (float*)(ws + 4096);         // 1 KB
    float* slots = (float*)(ws + 5120);         // 81920 B
    float* P2    = (float*)(ws + 87040);        // 163840 B
    float* G     = (float*)(ws + 250880);       // 131072 B
    bf16*  wkqb  = (bf16*) (ws + 381952);       // 131072 B (~513 KB total)

    k_init0<<<416, 256, 0, stream>>>(noise, smu, sls, nsw, nsb, niw, nib,
                                     Wq, Wk, G, slots, wkqb, Ug, Vg, P2, t0g, t1g);
    for (int it = 0; it < 3; it++){
        k_attn5<<<dim3(64, 16), 256, 0, stream>>>(obs, wkqb, Ug, Vg, niw, P2, t0g, t1g);
        k_slot<<<160, 256, 0, stream>>>(slots, P2, t0g, t1g, Wv, nmw, nmb,
                                        w1, b1, w2, b2, nsw, nsb, niw, nib,
                                        pw1, pb1, pw2, pb2, tw, tb, G,
                                        wkqb, Ug, Vg, d_out, (it == 2) ? 1 : 0);
    }
}